// Round 2
// baseline (667.940 us; speedup 1.0000x reference)
//
#include <hip/hip_runtime.h>
#include <math.h>

static constexpr int NNODES = 50000;
static constexpr int NEDGES = 600000;
static constexpr int D = 128;

// ---------------- CSR build ----------------

__global__ void count_kernel(const int* __restrict__ dst, int* __restrict__ cnt, int nE) {
  int i = blockIdx.x * blockDim.x + threadIdx.x;
  if (i < nE) atomicAdd(&cnt[dst[i]], 1);
}

// Single-block scan over n counts -> exclusive prefix (row_start), rs[n] = total.
__global__ void scan_kernel(const int* __restrict__ cnt, int* __restrict__ rs, int n) {
  __shared__ int wsum[16];
  __shared__ int s_carry;
  if (threadIdx.x == 0) s_carry = 0;
  __syncthreads();
  const int wid = threadIdx.x >> 6;
  const int lane = threadIdx.x & 63;
  for (int base = 0; base < n; base += 1024) {
    int i = base + (int)threadIdx.x;
    int v = (i < n) ? cnt[i] : 0;
    int incl = v;
#pragma unroll
    for (int off = 1; off < 64; off <<= 1) {
      int t = __shfl_up(incl, off);
      if (lane >= off) incl += t;
    }
    if (lane == 63) wsum[wid] = incl;
    __syncthreads();
    int woff = s_carry;
    for (int w = 0; w < wid; ++w) woff += wsum[w];
    if (i < n) rs[i] = woff + incl - v;   // exclusive
    __syncthreads();
    if (threadIdx.x == 1023) s_carry = woff + incl;
    __syncthreads();
  }
  if (threadIdx.x == 0) rs[n] = s_carry;
}

__global__ void fill_kernel(const int* __restrict__ src, const int* __restrict__ dst,
                            int* __restrict__ cursor, int* __restrict__ csr, int nE) {
  int i = blockIdx.x * blockDim.x + threadIdx.x;
  if (i < nE) {
    int d = dst[i];
    int p = atomicAdd(&cursor[d], 1);
    csr[p] = src[i];
  }
}

// ---------------- segment-max aggregation (CSR, no atomics) ----------------
// One wave (64 lanes) per destination node; each lane owns 2 features (float2).
__global__ __launch_bounds__(256) void agg_kernel(const float* __restrict__ x,
    const int* __restrict__ rs, const int* __restrict__ csr,
    float* __restrict__ agg, int n) {
  int gw = (int)((blockIdx.x * blockDim.x + threadIdx.x) >> 6);
  int lane = threadIdx.x & 63;
  if (gw >= n) return;
  int beg = rs[gw], end = rs[gw + 1];
  const float2* xx = (const float2*)x;
  float2 acc;
  acc.x = -INFINITY; acc.y = -INFINITY;
  int j = beg;
  for (; j + 4 <= end; j += 4) {
    int s0 = csr[j], s1 = csr[j + 1], s2 = csr[j + 2], s3 = csr[j + 3];
    float2 v0 = xx[s0 * 64 + lane];
    float2 v1 = xx[s1 * 64 + lane];
    float2 v2 = xx[s2 * 64 + lane];
    float2 v3 = xx[s3 * 64 + lane];
    acc.x = fmaxf(fmaxf(fmaxf(v0.x, v1.x), fmaxf(v2.x, v3.x)), acc.x);
    acc.y = fmaxf(fmaxf(fmaxf(v0.y, v1.y), fmaxf(v2.y, v3.y)), acc.y);
  }
  for (; j < end; ++j) {
    int s = csr[j];
    float2 v = xx[s * 64 + lane];
    acc.x = fmaxf(acc.x, v.x);
    acc.y = fmaxf(acc.y, v.y);
  }
  if (beg == end) { acc.x = 0.f; acc.y = 0.f; }  // isolated node -> 0 (PyG fill)
  ((float2*)agg)[gw * 64 + lane] = acc;
}

// ---------------- fused dual-GEMM + bias + relu ----------------
// out[r][f] = relu( sum_k agg[r][k]*W[k][f] + sum_k h[r][k]*R[k][f] + b[f] )
// 256 threads: tx (0..31) -> 4 features, ty (0..7) -> 8 rows. 64 rows/tile.
// W,R staged in 128 KiB LDS (1 block/CU); row operands from global (L1-resident).
#define COMP(v, kk) ((kk) == 0 ? (v).x : ((kk) == 1 ? (v).y : ((kk) == 2 ? (v).z : (v).w)))

__global__ __launch_bounds__(256) void gemm_kernel(
    const float* __restrict__ agg, const float* __restrict__ hin,
    const float* __restrict__ W, const float* __restrict__ R,
    const float* __restrict__ bias, float* __restrict__ out, int nrows) {
  __shared__ float sW[D * D];
  __shared__ float sR[D * D];
  for (int i = threadIdx.x * 4; i < D * D; i += 256 * 4) {
    *(float4*)&sW[i] = *(const float4*)&W[i];
    *(float4*)&sR[i] = *(const float4*)&R[i];
  }
  __syncthreads();

  const int tx = threadIdx.x & 31;
  const int ty = threadIdx.x >> 5;
  const int f0 = tx * 4;
  const float4 bv = *(const float4*)&bias[f0];
  const int ntiles = (nrows + 63) / 64;

  for (int t = blockIdx.x; t < ntiles; t += gridDim.x) {
    const int r0 = t * 64 + ty * 8;
    float acc[8][4];
#pragma unroll
    for (int r = 0; r < 8; ++r)
#pragma unroll
      for (int c = 0; c < 4; ++c) acc[r][c] = 0.f;

    const float* ap[8];
    const float* hp[8];
#pragma unroll
    for (int r = 0; r < 8; ++r) {
      int row = r0 + r; if (row > nrows - 1) row = nrows - 1;
      ap[r] = agg + (size_t)row * D;
      hp[r] = hin + (size_t)row * D;
    }

    for (int k = 0; k < D; k += 4) {
      float4 av[8], hv[8];
#pragma unroll
      for (int r = 0; r < 8; ++r) {
        av[r] = *(const float4*)(ap[r] + k);
        hv[r] = *(const float4*)(hp[r] + k);
      }
#pragma unroll
      for (int kk = 0; kk < 4; ++kk) {
        const float4 w = *(const float4*)&sW[(k + kk) * D + f0];
        const float4 rr = *(const float4*)&sR[(k + kk) * D + f0];
#pragma unroll
        for (int r = 0; r < 8; ++r) {
          const float a = COMP(av[r], kk);
          const float h = COMP(hv[r], kk);
          acc[r][0] = fmaf(a, w.x, fmaf(h, rr.x, acc[r][0]));
          acc[r][1] = fmaf(a, w.y, fmaf(h, rr.y, acc[r][1]));
          acc[r][2] = fmaf(a, w.z, fmaf(h, rr.z, acc[r][2]));
          acc[r][3] = fmaf(a, w.w, fmaf(h, rr.w, acc[r][3]));
        }
      }
    }

#pragma unroll
    for (int r = 0; r < 8; ++r) {
      int row = r0 + r;
      if (row < nrows) {
        float4 o;
        o.x = fmaxf(acc[r][0] + bv.x, 0.f);
        o.y = fmaxf(acc[r][1] + bv.y, 0.f);
        o.z = fmaxf(acc[r][2] + bv.z, 0.f);
        o.w = fmaxf(acc[r][3] + bv.w, 0.f);
        *(float4*)&out[(size_t)row * D + f0] = o;
      }
    }
  }
}

// ---------------- launch ----------------

extern "C" void kernel_launch(void* const* d_in, const int* in_sizes, int n_in,
                              void* d_out, int out_size, void* d_ws, size_t ws_size,
                              hipStream_t stream) {
  const float* x  = (const float*)d_in[0];
  const int*   ei = (const int*)d_in[1];
  const float* W1 = (const float*)d_in[2];
  const float* b1 = (const float*)d_in[3];
  const float* R1 = (const float*)d_in[4];
  const float* W2 = (const float*)d_in[5];
  const float* b2 = (const float*)d_in[6];
  const float* R2 = (const float*)d_in[7];
  float* out = (float*)d_out;

  const int* src = ei;
  const int* dst = ei + NEDGES;

  char* ws = (char*)d_ws;
  size_t off = 0;
  auto alloc = [&](size_t bytes) -> void* {
    off = (off + 511) & ~(size_t)511;
    void* p = ws + off;
    off += bytes;
    return p;
  };
  float* aggbuf = (float*)alloc(sizeof(float) * (size_t)NNODES * D);
  float* hbuf   = (float*)alloc(sizeof(float) * (size_t)NNODES * D);
  int* cnt      = (int*)alloc(sizeof(int) * NNODES);
  int* rs       = (int*)alloc(sizeof(int) * (NNODES + 1));
  int* cursor   = (int*)alloc(sizeof(int) * NNODES);
  int* csr      = (int*)alloc(sizeof(int) * NEDGES);

  // CSR build (once per call; edge_index restored before every timed launch)
  hipMemsetAsync(cnt, 0, sizeof(int) * NNODES, stream);
  count_kernel<<<(NEDGES + 255) / 256, 256, 0, stream>>>(dst, cnt, NEDGES);
  scan_kernel<<<1, 1024, 0, stream>>>(cnt, rs, NNODES);
  hipMemcpyAsync(cursor, rs, sizeof(int) * NNODES, hipMemcpyDeviceToDevice, stream);
  fill_kernel<<<(NEDGES + 255) / 256, 256, 0, stream>>>(src, dst, cursor, csr, NEDGES);

  auto layer = [&](const float* hin, const float* W, const float* R, const float* b,
                   float* hout) {
    agg_kernel<<<(NNODES + 3) / 4, 256, 0, stream>>>(hin, rs, csr, aggbuf, NNODES);
    gemm_kernel<<<256, 256, 0, stream>>>(aggbuf, hin, W, R, b, hout, NNODES);
  };

  layer(x,    W1, R1, b1, hbuf);
  layer(hbuf, W2, R2, b2, out);
  layer(out,  W2, R2, b2, hbuf);
  layer(hbuf, W2, R2, b2, out);
}

// Round 3
// 475.832 us; speedup vs baseline: 1.4037x; 1.4037x over previous
//
#include <hip/hip_runtime.h>
#include <math.h>

static constexpr int NNODES = 50000;
static constexpr int NEDGES = 600000;
static constexpr int D = 128;

typedef __attribute__((ext_vector_type(8))) short short8;   // 8 bf16 in 4 VGPRs
typedef __attribute__((ext_vector_type(4))) float f32x4;

static __device__ inline unsigned short f2bf_rne(float f) {
  unsigned u = __float_as_uint(f);
  unsigned r = (u + 0x7FFFu + ((u >> 16) & 1u)) >> 16;
  return (unsigned short)r;
}
static __device__ inline float bf2f(unsigned short s) {
  return __uint_as_float(((unsigned)s) << 16);
}

// ---------------- CSR build ----------------

__global__ void count_kernel(const int* __restrict__ dst, int* __restrict__ cnt, int nE) {
  int i = blockIdx.x * blockDim.x + threadIdx.x;
  if (i < nE) atomicAdd(&cnt[dst[i]], 1);
}

__global__ void scan_kernel(const int* __restrict__ cnt, int* __restrict__ rs, int n) {
  __shared__ int wsum[16];
  __shared__ int s_carry;
  if (threadIdx.x == 0) s_carry = 0;
  __syncthreads();
  const int wid = threadIdx.x >> 6;
  const int lane = threadIdx.x & 63;
  for (int base = 0; base < n; base += 1024) {
    int i = base + (int)threadIdx.x;
    int v = (i < n) ? cnt[i] : 0;
    int incl = v;
#pragma unroll
    for (int off = 1; off < 64; off <<= 1) {
      int t = __shfl_up(incl, off);
      if (lane >= off) incl += t;
    }
    if (lane == 63) wsum[wid] = incl;
    __syncthreads();
    int woff = s_carry;
    for (int w = 0; w < wid; ++w) woff += wsum[w];
    if (i < n) rs[i] = woff + incl - v;   // exclusive
    __syncthreads();
    if (threadIdx.x == 1023) s_carry = woff + incl;
    __syncthreads();
  }
  if (threadIdx.x == 0) rs[n] = s_carry;
}

__global__ void fill_kernel(const int* __restrict__ src, const int* __restrict__ dst,
                            int* __restrict__ cursor, int* __restrict__ csr, int nE) {
  int i = blockIdx.x * blockDim.x + threadIdx.x;
  if (i < nE) {
    int d = dst[i];
    int p = atomicAdd(&cursor[d], 1);
    csr[p] = src[i];
  }
}

// ---------------- segment-max aggregation (CSR, no atomics) ----------------
__global__ __launch_bounds__(256) void agg_kernel(const float* __restrict__ x,
    const int* __restrict__ rs, const int* __restrict__ csr,
    float* __restrict__ agg, int n) {
  int gw = (int)((blockIdx.x * blockDim.x + threadIdx.x) >> 6);
  int lane = threadIdx.x & 63;
  if (gw >= n) return;
  int beg = rs[gw], end = rs[gw + 1];
  const float2* xx = (const float2*)x;
  float2 acc;
  acc.x = -INFINITY; acc.y = -INFINITY;
  int j = beg;
  for (; j + 4 <= end; j += 4) {
    int s0 = csr[j], s1 = csr[j + 1], s2 = csr[j + 2], s3 = csr[j + 3];
    float2 v0 = xx[s0 * 64 + lane];
    float2 v1 = xx[s1 * 64 + lane];
    float2 v2 = xx[s2 * 64 + lane];
    float2 v3 = xx[s3 * 64 + lane];
    acc.x = fmaxf(fmaxf(fmaxf(v0.x, v1.x), fmaxf(v2.x, v3.x)), acc.x);
    acc.y = fmaxf(fmaxf(fmaxf(v0.y, v1.y), fmaxf(v2.y, v3.y)), acc.y);
  }
  for (; j < end; ++j) {
    int s = csr[j];
    float2 v = xx[s * 64 + lane];
    acc.x = fmaxf(acc.x, v.x);
    acc.y = fmaxf(acc.y, v.y);
  }
  if (beg == end) { acc.x = 0.f; acc.y = 0.f; }  // isolated node -> 0 (PyG fill)
  ((float2*)agg)[gw * 64 + lane] = acc;
}

// ---------------- weight pre-pack into MFMA B-fragment layout ----------------
// B-fragment (16x16x32): lane l holds B[k = ks*32 + (l>>4)*8 + e][j = jb*16 + (l&15)]
// Packed flat index: ((jb*4 + ks)*64 + lane)*8 + e   -> per-lane 16B coalesced loads.
__global__ void pack_kernel(const float* __restrict__ Wm,
                            unsigned short* __restrict__ hi,
                            unsigned short* __restrict__ lo) {
  int tid = blockIdx.x * blockDim.x + threadIdx.x;  // 0..2047
  if (tid >= 2048) return;
  int jb = tid >> 8;
  int ks = (tid >> 6) & 3;
  int lane = tid & 63;
  int j = jb * 16 + (lane & 15);
  int k0 = ks * 32 + (lane >> 4) * 8;
#pragma unroll
  for (int e = 0; e < 8; ++e) {
    float v = Wm[(k0 + e) * D + j];
    unsigned short h = f2bf_rne(v);
    float rem = v - bf2f(h);
    unsigned short l = f2bf_rne(rem);
    hi[tid * 8 + e] = h;
    lo[tid * 8 + e] = l;
  }
}

// ---------------- fused dual-GEMM + bias + relu (bf16 MFMA, hi/lo split) ----------------
// out = relu(agg@W + h@R + b). 4 waves/block, 32 rows/wave (2 groups of 16), no LDS.
// Split precision: X ~= Xhi + Xlo (bf16); X@Y ~= Xhi@Yhi + Xlo@Yhi + Xhi@Ylo.
__global__ __launch_bounds__(256) void gemm_mfma(
    const float* __restrict__ agg, const float* __restrict__ hin,
    const unsigned short* __restrict__ Whi, const unsigned short* __restrict__ Wlo,
    const unsigned short* __restrict__ Rhi, const unsigned short* __restrict__ Rlo,
    const float* __restrict__ bias, float* __restrict__ out, int nrows) {
  const int lane = threadIdx.x & 63;
  const int wv = threadIdx.x >> 6;       // 0..3
  const int m_lo = lane & 15;
  const int kgrp = lane >> 4;            // 0..3
  const int r_base = blockIdx.x * 128 + wv * 32;

  f32x4 acc[2][8];
#pragma unroll
  for (int g = 0; g < 2; ++g)
#pragma unroll
    for (int jb = 0; jb < 8; ++jb) acc[g][jb] = (f32x4)0.f;

  float bv[8];
#pragma unroll
  for (int jb = 0; jb < 8; ++jb) bv[jb] = bias[jb * 16 + m_lo];

  for (int ks = 0; ks < 4; ++ks) {
    short8 fa_hi[2], fa_lo[2], fh_hi[2], fh_lo[2];
#pragma unroll
    for (int g = 0; g < 2; ++g) {
      int row = r_base + g * 16 + m_lo;
      if (row >= nrows) row = nrows - 1;
      const float* ap = agg + (size_t)row * D + ks * 32 + kgrp * 8;
      const float* hp = hin + (size_t)row * D + ks * 32 + kgrp * 8;
      float av[8], hv[8];
      *(f32x4*)&av[0] = *(const f32x4*)(ap);
      *(f32x4*)&av[4] = *(const f32x4*)(ap + 4);
      *(f32x4*)&hv[0] = *(const f32x4*)(hp);
      *(f32x4*)&hv[4] = *(const f32x4*)(hp + 4);
#pragma unroll
      for (int e = 0; e < 8; ++e) {
        unsigned short h1 = f2bf_rne(av[e]);
        fa_hi[g][e] = (short)h1;
        fa_lo[g][e] = (short)f2bf_rne(av[e] - bf2f(h1));
        unsigned short h2 = f2bf_rne(hv[e]);
        fh_hi[g][e] = (short)h2;
        fh_lo[g][e] = (short)f2bf_rne(hv[e] - bf2f(h2));
      }
    }
#pragma unroll
    for (int jb = 0; jb < 8; ++jb) {
      const int pidx = ((jb * 4 + ks) * 64 + lane) * 8;
      short8 bwhi = *(const short8*)(Whi + pidx);
      short8 bwlo = *(const short8*)(Wlo + pidx);
      short8 brhi = *(const short8*)(Rhi + pidx);
      short8 brlo = *(const short8*)(Rlo + pidx);
#pragma unroll
      for (int g = 0; g < 2; ++g) {
        acc[g][jb] = __builtin_amdgcn_mfma_f32_16x16x32_bf16(fa_hi[g], bwhi, acc[g][jb], 0, 0, 0);
        acc[g][jb] = __builtin_amdgcn_mfma_f32_16x16x32_bf16(fa_lo[g], bwhi, acc[g][jb], 0, 0, 0);
        acc[g][jb] = __builtin_amdgcn_mfma_f32_16x16x32_bf16(fa_hi[g], bwlo, acc[g][jb], 0, 0, 0);
        acc[g][jb] = __builtin_amdgcn_mfma_f32_16x16x32_bf16(fh_hi[g], brhi, acc[g][jb], 0, 0, 0);
        acc[g][jb] = __builtin_amdgcn_mfma_f32_16x16x32_bf16(fh_lo[g], brhi, acc[g][jb], 0, 0, 0);
        acc[g][jb] = __builtin_amdgcn_mfma_f32_16x16x32_bf16(fh_hi[g], brlo, acc[g][jb], 0, 0, 0);
      }
    }
  }

  // D layout: col = lane&15, row-in-tile = kgrp*4 + reg
#pragma unroll
  for (int g = 0; g < 2; ++g) {
#pragma unroll
    for (int jb = 0; jb < 8; ++jb) {
#pragma unroll
      for (int r = 0; r < 4; ++r) {
        int row = r_base + g * 16 + kgrp * 4 + r;
        if (row < nrows) {
          float v = acc[g][jb][r] + bv[jb];
          out[(size_t)row * D + jb * 16 + m_lo] = fmaxf(v, 0.f);
        }
      }
    }
  }
}

// ---------------- launch ----------------

extern "C" void kernel_launch(void* const* d_in, const int* in_sizes, int n_in,
                              void* d_out, int out_size, void* d_ws, size_t ws_size,
                              hipStream_t stream) {
  const float* x  = (const float*)d_in[0];
  const int*   ei = (const int*)d_in[1];
  const float* W1 = (const float*)d_in[2];
  const float* b1 = (const float*)d_in[3];
  const float* R1 = (const float*)d_in[4];
  const float* W2 = (const float*)d_in[5];
  const float* b2 = (const float*)d_in[6];
  const float* R2 = (const float*)d_in[7];
  float* out = (float*)d_out;

  const int* src = ei;
  const int* dst = ei + NEDGES;

  char* ws = (char*)d_ws;
  size_t off = 0;
  auto alloc = [&](size_t bytes) -> void* {
    off = (off + 511) & ~(size_t)511;
    void* p = ws + off;
    off += bytes;
    return p;
  };
  float* aggbuf = (float*)alloc(sizeof(float) * (size_t)NNODES * D);
  float* hbuf   = (float*)alloc(sizeof(float) * (size_t)NNODES * D);
  int* cnt      = (int*)alloc(sizeof(int) * NNODES);
  int* rs       = (int*)alloc(sizeof(int) * (NNODES + 1));
  int* cursor   = (int*)alloc(sizeof(int) * NNODES);
  int* csr      = (int*)alloc(sizeof(int) * NEDGES);
  const int PACKN = 2048 * 8;  // 16384 bf16 per matrix
  unsigned short* w1hi = (unsigned short*)alloc(sizeof(short) * PACKN);
  unsigned short* w1lo = (unsigned short*)alloc(sizeof(short) * PACKN);
  unsigned short* r1hi = (unsigned short*)alloc(sizeof(short) * PACKN);
  unsigned short* r1lo = (unsigned short*)alloc(sizeof(short) * PACKN);
  unsigned short* w2hi = (unsigned short*)alloc(sizeof(short) * PACKN);
  unsigned short* w2lo = (unsigned short*)alloc(sizeof(short) * PACKN);
  unsigned short* r2hi = (unsigned short*)alloc(sizeof(short) * PACKN);
  unsigned short* r2lo = (unsigned short*)alloc(sizeof(short) * PACKN);

  // weight pre-pack (independent of CSR build)
  pack_kernel<<<8, 256, 0, stream>>>(W1, w1hi, w1lo);
  pack_kernel<<<8, 256, 0, stream>>>(R1, r1hi, r1lo);
  pack_kernel<<<8, 256, 0, stream>>>(W2, w2hi, w2lo);
  pack_kernel<<<8, 256, 0, stream>>>(R2, r2hi, r2lo);

  // CSR build (once per call; edge_index restored before every timed launch)
  hipMemsetAsync(cnt, 0, sizeof(int) * NNODES, stream);
  count_kernel<<<(NEDGES + 255) / 256, 256, 0, stream>>>(dst, cnt, NEDGES);
  scan_kernel<<<1, 1024, 0, stream>>>(cnt, rs, NNODES);
  hipMemcpyAsync(cursor, rs, sizeof(int) * NNODES, hipMemcpyDeviceToDevice, stream);
  fill_kernel<<<(NEDGES + 255) / 256, 256, 0, stream>>>(src, dst, cursor, csr, NEDGES);

  const int gemm_grid = (NNODES + 127) / 128;  // 391

  auto layer = [&](const float* hin,
                   const unsigned short* whi, const unsigned short* wlo,
                   const unsigned short* rhi, const unsigned short* rlo,
                   const float* b, float* hout) {
    agg_kernel<<<(NNODES + 3) / 4, 256, 0, stream>>>(hin, rs, csr, aggbuf, NNODES);
    gemm_mfma<<<gemm_grid, 256, 0, stream>>>(aggbuf, hin, whi, wlo, rhi, rlo, b, hout, NNODES);
  };

  layer(x,    w1hi, w1lo, r1hi, r1lo, b1, hbuf);
  layer(hbuf, w2hi, w2lo, r2hi, r2lo, b2, out);
  layer(out,  w2hi, w2lo, r2hi, r2lo, b2, hbuf);
  layer(hbuf, w2hi, w2lo, r2hi, r2lo, b2, out);
}

// Round 4
// 415.265 us; speedup vs baseline: 1.6085x; 1.1459x over previous
//
#include <hip/hip_runtime.h>
#include <math.h>

static constexpr int NNODES = 50000;
static constexpr int NEDGES = 600000;
static constexpr int D = 128;
static constexpr int NPART = (NNODES + 255) / 256;  // 196

typedef __attribute__((ext_vector_type(8))) short short8;   // 8 bf16 in 4 VGPRs
typedef __attribute__((ext_vector_type(4))) float f32x4;

static __device__ inline unsigned short f2bf_rne(float f) {
  unsigned u = __float_as_uint(f);
  unsigned r = (u + 0x7FFFu + ((u >> 16) & 1u)) >> 16;
  return (unsigned short)r;
}
static __device__ inline float bf2f(unsigned short s) {
  return __uint_as_float(((unsigned)s) << 16);
}

// ---------------- CSR build ----------------

__global__ void count_kernel(const int* __restrict__ dst, int* __restrict__ cnt, int nE) {
  int i = blockIdx.x * blockDim.x + threadIdx.x;
  if (i < nE) atomicAdd(&cnt[dst[i]], 1);
}

// 3-stage parallel exclusive scan of cnt[0..n) -> rs (and cursor copy).
__global__ void scan_partial(const int* __restrict__ cnt, int* __restrict__ part, int n) {
  int i = blockIdx.x * 256 + threadIdx.x;
  int v = (i < n) ? cnt[i] : 0;
#pragma unroll
  for (int off = 32; off > 0; off >>= 1) v += __shfl_down(v, off);
  __shared__ int ws[4];
  int wid = threadIdx.x >> 6, lane = threadIdx.x & 63;
  if (lane == 0) ws[wid] = v;
  __syncthreads();
  if (threadIdx.x == 0) part[blockIdx.x] = ws[0] + ws[1] + ws[2] + ws[3];
}

__global__ void scan_root(const int* __restrict__ part, int* __restrict__ pscan,
                          int* __restrict__ rs_last, int np) {
  int i = threadIdx.x;                 // single block, 256 threads, np <= 256
  int v = (i < np) ? part[i] : 0;
  int incl = v;
  int lane = i & 63, wid = i >> 6;
#pragma unroll
  for (int off = 1; off < 64; off <<= 1) {
    int t = __shfl_up(incl, off);
    if (lane >= off) incl += t;
  }
  __shared__ int ws[4];
  if (lane == 63) ws[wid] = incl;
  __syncthreads();
  int woff = 0;
  for (int w = 0; w < wid; ++w) woff += ws[w];
  if (i < np) pscan[i] = woff + incl - v;  // exclusive
  if (i == 0) *rs_last = ws[0] + ws[1] + ws[2] + ws[3];
}

__global__ void scan_apply(const int* __restrict__ cnt, const int* __restrict__ pscan,
                           int* __restrict__ rs, int* __restrict__ cursor, int n) {
  int i = blockIdx.x * 256 + threadIdx.x;
  int v = (i < n) ? cnt[i] : 0;
  int incl = v;
  int lane = threadIdx.x & 63, wid = threadIdx.x >> 6;
#pragma unroll
  for (int off = 1; off < 64; off <<= 1) {
    int t = __shfl_up(incl, off);
    if (lane >= off) incl += t;
  }
  __shared__ int ws[4];
  if (lane == 63) ws[wid] = incl;
  __syncthreads();
  int woff = pscan[blockIdx.x];
  for (int w = 0; w < wid; ++w) woff += ws[w];
  int ex = woff + incl - v;
  if (i < n) { rs[i] = ex; cursor[i] = ex; }
}

__global__ void fill_kernel(const int* __restrict__ src, const int* __restrict__ dst,
                            int* __restrict__ cursor, int* __restrict__ csr, int nE) {
  int i = blockIdx.x * blockDim.x + threadIdx.x;
  if (i < nE) {
    int d = dst[i];
    int p = atomicAdd(&cursor[d], 1);
    csr[p] = src[i];
  }
}

// ---------------- segment-max aggregation (CSR, no atomics) ----------------
// One wave per destination node; lane owns 2 features; 8-deep gather unroll.
__global__ __launch_bounds__(256) void agg_kernel(const float* __restrict__ x,
    const int* __restrict__ rs, const int* __restrict__ csr,
    float* __restrict__ agg, int n) {
  int gw = (int)((blockIdx.x * blockDim.x + threadIdx.x) >> 6);
  int lane = threadIdx.x & 63;
  if (gw >= n) return;
  int beg = rs[gw], end = rs[gw + 1];
  const float2* xx = (const float2*)x;
  float2 acc;
  acc.x = -INFINITY; acc.y = -INFINITY;
  int j = beg;
  for (; j + 8 <= end; j += 8) {
    int s[8];
#pragma unroll
    for (int u = 0; u < 8; ++u) s[u] = csr[j + u];
    float2 v[8];
#pragma unroll
    for (int u = 0; u < 8; ++u) v[u] = xx[s[u] * 64 + lane];
#pragma unroll
    for (int u = 0; u < 8; ++u) {
      acc.x = fmaxf(acc.x, v[u].x);
      acc.y = fmaxf(acc.y, v[u].y);
    }
  }
  for (; j + 2 <= end; j += 2) {
    int s0 = csr[j], s1 = csr[j + 1];
    float2 v0 = xx[s0 * 64 + lane];
    float2 v1 = xx[s1 * 64 + lane];
    acc.x = fmaxf(acc.x, fmaxf(v0.x, v1.x));
    acc.y = fmaxf(acc.y, fmaxf(v0.y, v1.y));
  }
  for (; j < end; ++j) {
    int s = csr[j];
    float2 v = xx[s * 64 + lane];
    acc.x = fmaxf(acc.x, v.x);
    acc.y = fmaxf(acc.y, v.y);
  }
  if (beg == end) { acc.x = 0.f; acc.y = 0.f; }  // isolated node -> 0 (PyG fill)
  ((float2*)agg)[gw * 64 + lane] = acc;
}

// ---------------- weight pre-pack into MFMA B-fragment layout ----------------
// B-fragment (16x16x32): lane l holds B[k = ks*32 + (l>>4)*8 + e][j = jb*16 + (l&15)]
// Packed flat index: ((jb*4 + ks)*64 + lane)*8 + e -> per-lane 16B coalesced loads.
struct PackArgs {
  const float* src[4];
  unsigned short* hi[4];
  unsigned short* lo[4];
};

__global__ void pack_all(PackArgs pa) {
  int mat = blockIdx.x >> 3;                       // 0..3
  int tid = (blockIdx.x & 7) * 256 + threadIdx.x;  // 0..2047
  const float* Wm = pa.src[mat];
  unsigned short* hi = pa.hi[mat];
  unsigned short* lo = pa.lo[mat];
  int jb = tid >> 8;
  int ks = (tid >> 6) & 3;
  int lane = tid & 63;
  int j = jb * 16 + (lane & 15);
  int k0 = ks * 32 + (lane >> 4) * 8;
#pragma unroll
  for (int e = 0; e < 8; ++e) {
    float v = Wm[(k0 + e) * D + j];
    unsigned short h = f2bf_rne(v);
    float rem = v - bf2f(h);
    unsigned short l = f2bf_rne(rem);
    hi[tid * 8 + e] = h;
    lo[tid * 8 + e] = l;
  }
}

// ---------------- fused dual-GEMM + bias + relu (bf16 MFMA, hi/lo split) ----------------
// out = relu(agg@W + h@R + b). 4 waves/block, 32 rows/wave (2 groups of 16), no LDS.
// Split precision: X ~= Xhi + Xlo (bf16); X@Y ~= Xhi@Yhi + Xlo@Yhi + Xhi@Ylo.
__global__ __launch_bounds__(256) void gemm_mfma(
    const float* __restrict__ agg, const float* __restrict__ hin,
    const unsigned short* __restrict__ Whi, const unsigned short* __restrict__ Wlo,
    const unsigned short* __restrict__ Rhi, const unsigned short* __restrict__ Rlo,
    const float* __restrict__ bias, float* __restrict__ out, int nrows) {
  const int lane = threadIdx.x & 63;
  const int wv = threadIdx.x >> 6;       // 0..3
  const int m_lo = lane & 15;
  const int kgrp = lane >> 4;            // 0..3
  const int r_base = blockIdx.x * 128 + wv * 32;

  f32x4 acc[2][8];
#pragma unroll
  for (int g = 0; g < 2; ++g)
#pragma unroll
    for (int jb = 0; jb < 8; ++jb) acc[g][jb] = (f32x4)0.f;

  float bv[8];
#pragma unroll
  for (int jb = 0; jb < 8; ++jb) bv[jb] = bias[jb * 16 + m_lo];

  for (int ks = 0; ks < 4; ++ks) {
    short8 fa_hi[2], fa_lo[2], fh_hi[2], fh_lo[2];
#pragma unroll
    for (int g = 0; g < 2; ++g) {
      int row = r_base + g * 16 + m_lo;
      if (row >= nrows) row = nrows - 1;
      const float* ap = agg + (size_t)row * D + ks * 32 + kgrp * 8;
      const float* hp = hin + (size_t)row * D + ks * 32 + kgrp * 8;
      float av[8], hv[8];
      *(f32x4*)&av[0] = *(const f32x4*)(ap);
      *(f32x4*)&av[4] = *(const f32x4*)(ap + 4);
      *(f32x4*)&hv[0] = *(const f32x4*)(hp);
      *(f32x4*)&hv[4] = *(const f32x4*)(hp + 4);
#pragma unroll
      for (int e = 0; e < 8; ++e) {
        unsigned short h1 = f2bf_rne(av[e]);
        fa_hi[g][e] = (short)h1;
        fa_lo[g][e] = (short)f2bf_rne(av[e] - bf2f(h1));
        unsigned short h2 = f2bf_rne(hv[e]);
        fh_hi[g][e] = (short)h2;
        fh_lo[g][e] = (short)f2bf_rne(hv[e] - bf2f(h2));
      }
    }
#pragma unroll
    for (int jb = 0; jb < 8; ++jb) {
      const int pidx = ((jb * 4 + ks) * 64 + lane) * 8;
      short8 bwhi = *(const short8*)(Whi + pidx);
      short8 bwlo = *(const short8*)(Wlo + pidx);
      short8 brhi = *(const short8*)(Rhi + pidx);
      short8 brlo = *(const short8*)(Rlo + pidx);
#pragma unroll
      for (int g = 0; g < 2; ++g) {
        acc[g][jb] = __builtin_amdgcn_mfma_f32_16x16x32_bf16(fa_hi[g], bwhi, acc[g][jb], 0, 0, 0);
        acc[g][jb] = __builtin_amdgcn_mfma_f32_16x16x32_bf16(fa_lo[g], bwhi, acc[g][jb], 0, 0, 0);
        acc[g][jb] = __builtin_amdgcn_mfma_f32_16x16x32_bf16(fa_hi[g], bwlo, acc[g][jb], 0, 0, 0);
        acc[g][jb] = __builtin_amdgcn_mfma_f32_16x16x32_bf16(fh_hi[g], brhi, acc[g][jb], 0, 0, 0);
        acc[g][jb] = __builtin_amdgcn_mfma_f32_16x16x32_bf16(fh_lo[g], brhi, acc[g][jb], 0, 0, 0);
        acc[g][jb] = __builtin_amdgcn_mfma_f32_16x16x32_bf16(fh_hi[g], brlo, acc[g][jb], 0, 0, 0);
      }
    }
  }

  // D layout: col = lane&15, row-in-tile = kgrp*4 + reg
#pragma unroll
  for (int g = 0; g < 2; ++g) {
#pragma unroll
    for (int jb = 0; jb < 8; ++jb) {
#pragma unroll
      for (int r = 0; r < 4; ++r) {
        int row = r_base + g * 16 + kgrp * 4 + r;
        if (row < nrows) {
          float v = acc[g][jb][r] + bv[jb];
          out[(size_t)row * D + jb * 16 + m_lo] = fmaxf(v, 0.f);
        }
      }
    }
  }
}

// ---------------- launch ----------------

extern "C" void kernel_launch(void* const* d_in, const int* in_sizes, int n_in,
                              void* d_out, int out_size, void* d_ws, size_t ws_size,
                              hipStream_t stream) {
  const float* x  = (const float*)d_in[0];
  const int*   ei = (const int*)d_in[1];
  const float* W1 = (const float*)d_in[2];
  const float* b1 = (const float*)d_in[3];
  const float* R1 = (const float*)d_in[4];
  const float* W2 = (const float*)d_in[5];
  const float* b2 = (const float*)d_in[6];
  const float* R2 = (const float*)d_in[7];
  float* out = (float*)d_out;

  const int* src = ei;
  const int* dst = ei + NEDGES;

  char* ws = (char*)d_ws;
  size_t off = 0;
  auto alloc = [&](size_t bytes) -> void* {
    off = (off + 511) & ~(size_t)511;
    void* p = ws + off;
    off += bytes;
    return p;
  };
  float* aggbuf = (float*)alloc(sizeof(float) * (size_t)NNODES * D);
  float* hbuf   = (float*)alloc(sizeof(float) * (size_t)NNODES * D);
  int* cnt      = (int*)alloc(sizeof(int) * NNODES);
  int* rs       = (int*)alloc(sizeof(int) * (NNODES + 1));
  int* cursor   = (int*)alloc(sizeof(int) * NNODES);
  int* csr      = (int*)alloc(sizeof(int) * NEDGES);
  int* part     = (int*)alloc(sizeof(int) * NPART);
  int* pscan    = (int*)alloc(sizeof(int) * NPART);
  const int PACKN = 2048 * 8;  // 16384 bf16 per matrix
  unsigned short* w1hi = (unsigned short*)alloc(sizeof(short) * PACKN);
  unsigned short* w1lo = (unsigned short*)alloc(sizeof(short) * PACKN);
  unsigned short* r1hi = (unsigned short*)alloc(sizeof(short) * PACKN);
  unsigned short* r1lo = (unsigned short*)alloc(sizeof(short) * PACKN);
  unsigned short* w2hi = (unsigned short*)alloc(sizeof(short) * PACKN);
  unsigned short* w2lo = (unsigned short*)alloc(sizeof(short) * PACKN);
  unsigned short* r2hi = (unsigned short*)alloc(sizeof(short) * PACKN);
  unsigned short* r2lo = (unsigned short*)alloc(sizeof(short) * PACKN);

  // weight pre-pack (independent of CSR build), all 4 matrices in one launch
  PackArgs pa;
  pa.src[0] = W1; pa.hi[0] = w1hi; pa.lo[0] = w1lo;
  pa.src[1] = R1; pa.hi[1] = r1hi; pa.lo[1] = r1lo;
  pa.src[2] = W2; pa.hi[2] = w2hi; pa.lo[2] = w2lo;
  pa.src[3] = R2; pa.hi[3] = r2hi; pa.lo[3] = r2lo;
  pack_all<<<32, 256, 0, stream>>>(pa);

  // CSR build (once per call; edge_index restored before every timed launch)
  hipMemsetAsync(cnt, 0, sizeof(int) * NNODES, stream);
  count_kernel<<<(NEDGES + 255) / 256, 256, 0, stream>>>(dst, cnt, NEDGES);
  scan_partial<<<NPART, 256, 0, stream>>>(cnt, part, NNODES);
  scan_root<<<1, 256, 0, stream>>>(part, pscan, &rs[NNODES], NPART);
  scan_apply<<<NPART, 256, 0, stream>>>(cnt, pscan, rs, cursor, NNODES);
  fill_kernel<<<(NEDGES + 255) / 256, 256, 0, stream>>>(src, dst, cursor, csr, NEDGES);

  const int gemm_grid = (NNODES + 127) / 128;  // 391

  auto layer = [&](const float* hin,
                   const unsigned short* whi, const unsigned short* wlo,
                   const unsigned short* rhi, const unsigned short* rlo,
                   const float* b, float* hout) {
    agg_kernel<<<(NNODES + 3) / 4, 256, 0, stream>>>(hin, rs, csr, aggbuf, NNODES);
    gemm_mfma<<<gemm_grid, 256, 0, stream>>>(aggbuf, hin, whi, wlo, rhi, rlo, b, hout, NNODES);
  };

  layer(x,    w1hi, w1lo, r1hi, r1lo, b1, hbuf);
  layer(hbuf, w2hi, w2lo, r2hi, r2lo, b2, out);
  layer(out,  w2hi, w2lo, r2hi, r2lo, b2, hbuf);
  layer(hbuf, w2hi, w2lo, r2hi, r2lo, b2, out);
}